// Round 8
// baseline (204.462 us; speedup 1.0000x reference)
//
#include <hip/hip_runtime.h>
#include <cstdint>

// Reference geometry (fixed problem)
constexpr int B_ = 4, H_ = 8, D_ = 64, L_ = 4096;
constexpr int BH = B_ * H_;          // 32
constexpr int U_PART = 25;           // FACTOR * ceil(log(64))
constexpr int TOPU = 45;             // FACTOR * ceil(log(4096))
constexpr int CHUNK = 128;           // keys per update chunk (LDS-staged)
constexpr int NCH = L_ / CHUNK;      // 32 chunks
constexpr int PSTRIDE = 68;          // acc[64], max, sum, pad to 16B-aligned stride

#define JAX_THREEFRY_PARTITIONABLE 1

// ---------------- Threefry-2x32 (exact JAX semantics) ----------------
__host__ __device__ inline void tf2x32(uint32_t k0, uint32_t k1,
                                       uint32_t x0, uint32_t x1,
                                       uint32_t& y0, uint32_t& y1) {
  const uint32_t ks2 = k0 ^ k1 ^ 0x1BD11BDAu;
  uint32_t v0 = x0 + k0, v1 = x1 + k1;
#define RND(r) { v0 += v1; v1 = (v1 << (r)) | (v1 >> (32 - (r))); v1 ^= v0; }
  RND(13) RND(15) RND(26) RND(6)
  v0 += k1; v1 += ks2 + 1u;
  RND(17) RND(29) RND(16) RND(24)
  v0 += ks2; v1 += k0 + 2u;
  RND(13) RND(15) RND(26) RND(6)
  v0 += k0; v1 += k1 + 3u;
  RND(17) RND(29) RND(16) RND(24)
  v0 += k1; v1 += ks2 + 4u;
  RND(13) RND(15) RND(26) RND(6)
  v0 += ks2; v1 += k0 + 5u;
#undef RND
  y0 = v0; y1 = v1;
}

__global__ __launch_bounds__(256) void sample_idx_kernel(int* __restrict__ idx,
                                                         uint32_t k2a, uint32_t k2b) {
#if JAX_THREEFRY_PARTITIONABLE
  int i = blockIdx.x * 256 + threadIdx.x;
  if (i >= L_ * U_PART) return;
  uint32_t y0, y1;
  tf2x32(k2a, k2b, 0u, (uint32_t)i, y0, y1);
  idx[i] = (int)((y0 ^ y1) & 4095u);
#else
  int j = blockIdx.x * 256 + threadIdx.x;
  const int half = (L_ * U_PART) / 2;   // 51200
  if (j >= half) return;
  uint32_t y0, y1;
  tf2x32(k2a, k2b, (uint32_t)j, (uint32_t)(j + half), y0, y1);
  idx[j] = (int)(y0 & 4095u);
  idx[j + half] = (int)(y1 & 4095u);
#endif
}

// ---------------- Transpose + scale: (BH, D, L) -> (BH, L, D) ----------------
__global__ __launch_bounds__(256) void transpose_scale(
    const float* __restrict__ q, const float* __restrict__ k, const float* __restrict__ v,
    float* __restrict__ qt, float* __restrict__ kt, float* __restrict__ vt) {
  const float* src; float* dst; float scale;
  if (blockIdx.z == 0)      { src = q; dst = qt; scale = 1.0f / 512.0f; }
  else if (blockIdx.z == 1) { src = k; dst = kt; scale = 1.0f / 64.0f; }
  else                      { src = v; dst = vt; scale = 1.0f / 64.0f; }
  const int bh = blockIdx.y;
  const int l0 = blockIdx.x * 64;
  __shared__ float tile[64][65];
  const float* s = src + (size_t)bh * D_ * L_;
  float* d = dst + (size_t)bh * L_ * D_;
  const int t = threadIdx.x;
#pragma unroll
  for (int i = 0; i < 16; i++) {
    int li = i * 256 + t;          // 0..4095
    int dd = li >> 6, ll = li & 63;
    tile[dd][ll] = s[(size_t)dd * L_ + l0 + ll] * scale;
  }
  __syncthreads();
#pragma unroll
  for (int i = 0; i < 16; i++) {
    int li = i * 256 + t;
    int ll = li >> 6, dd = li & 63;
    d[(size_t)(l0 + ll) * D_ + dd] = tile[dd][ll];
  }
}

// ---------------- M[b,h,l] = max_s QK - sum_s QK / 4096 ----------------
// 4 lanes per l (16-float q fragment each): 16 FMA per 2 shfl -> DS pipe 8x lighter.
// XCD-swizzled: each XCD owns 4 bh (kt stays L2-resident).
__global__ __launch_bounds__(256) void m_kernel(const float* __restrict__ qt,
                                                const float* __restrict__ kt,
                                                const int* __restrict__ idx,
                                                float* __restrict__ M) {
  const int t = threadIdx.x;
  const int w = t >> 6, lane = t & 63;
  const int g = lane >> 2, gl = lane & 3;      // 16 groups of 4 lanes
  const int xcd = blockIdx.x & 7;              // blockIdx%8 = XCD [m09]
  const int slot = blockIdx.x >> 3;            // 0..255
  const int bh = xcd * 4 + (slot >> 6);
  const int l = (slot & 63) * 64 + w * 16 + g;
  const int gidx = bh * L_ + l;
  const float* qtb = qt + (size_t)bh * L_ * D_;
  const float* ktb = kt + (size_t)bh * L_ * D_;
  const float* qr = qtb + (size_t)l * D_ + gl * 16;
  const float4 q0 = *(const float4*)(qr);
  const float4 q1 = *(const float4*)(qr + 4);
  const float4 q2 = *(const float4*)(qr + 8);
  const float4 q3 = *(const float4*)(qr + 12);
  const int* ip = idx + l * U_PART;
  float mx = -INFINITY, sm = 0.0f;
#pragma unroll 5
  for (int s = 0; s < U_PART; s++) {
    const int ki = ip[s];
    const float* kr = ktb + (size_t)ki * D_ + gl * 16;
    const float4 k0 = *(const float4*)(kr);
    const float4 k1 = *(const float4*)(kr + 4);
    const float4 k2 = *(const float4*)(kr + 8);
    const float4 k3 = *(const float4*)(kr + 12);
    float p = q0.x * k0.x + q0.y * k0.y + q0.z * k0.z + q0.w * k0.w
            + q1.x * k1.x + q1.y * k1.y + q1.z * k1.z + q1.w * k1.w
            + q2.x * k2.x + q2.y * k2.y + q2.z * k2.z + q2.w * k2.w
            + q3.x * k3.x + q3.y * k3.y + q3.z * k3.z + q3.w * k3.w;
    p += __shfl_xor(p, 1, 64);
    p += __shfl_xor(p, 2, 64);
    mx = fmaxf(mx, p);
    sm += p;
  }
  if (gl == 0) M[gidx] = mx - sm * (1.0f / 4096.0f);
}

// ---------------- top-45 per (b,h), register-resident, SORTED DESC by index ----------------
__global__ __launch_bounds__(256) void topk_kernel(const float* __restrict__ M,
                                                   int* __restrict__ ssel_g) {
  const int bh = blockIdx.x, t = threadIdx.x;
  const int w = t >> 6, lane = t & 63;
  const float* Mb = M + (size_t)bh * L_;
  const int base = w * 1024 + lane;
  uint32_t v[16];
#pragma unroll
  for (int j = 0; j < 16; j++) {          // coalesced: lanes read consecutive
    uint32_t b = __float_as_uint(Mb[base + j * 64]);
    v[j] = b ^ ((b & 0x80000000u) ? 0xFFFFFFFFu : 0x80000000u);
  }
  __shared__ unsigned long long red[4];
  __shared__ int picks[TOPU];
  for (int it = 0; it < TOPU; it++) {
    unsigned long long best = 0ull;
#pragma unroll
    for (int j = 0; j < 16; j++) {
      unsigned long long key = ((unsigned long long)v[j] << 32)
                             | (uint32_t)(L_ - 1 - (base + j * 64));
      best = (key > best) ? key : best;
    }
#pragma unroll
    for (int off = 32; off; off >>= 1) {
      unsigned long long o = __shfl_xor(best, off, 64);
      best = (o > best) ? o : best;
    }
    if (lane == 0) red[w] = best;
    __syncthreads();
    unsigned long long g = red[0];
    if (red[1] > g) g = red[1];
    if (red[2] > g) g = red[2];
    if (red[3] > g) g = red[3];
    const int bi = L_ - 1 - (int)(g & 0xFFFFFFFFu);
    if (t == 0) picks[it] = bi;
    if ((bi >> 10) == w && (bi & 63) == lane) {   // remove winner
      const int slot = (bi >> 6) & 15;
#pragma unroll
      for (int j = 0; j < 16; j++) if (slot == j) v[j] = 0u;
    }
    __syncthreads();
  }
  // rank-sort descending by key index (indices distinct)
  if (t < TOPU) {
    int my = picks[t];
    int rank = 0;
    for (int j = 0; j < TOPU; j++) rank += (picks[j] > my);
    ssel_g[bh * TOPU + rank] = my;
  }
}

// ---------------- out[bh,d,l] = cumsum_l v[bh,d,l] / 64 ----------------
__global__ __launch_bounds__(256) void cumsum_kernel(const float* __restrict__ v,
                                                     float* __restrict__ out) {
  const int row = blockIdx.x;                 // BH*D rows
  const float* src = v + (size_t)row * L_;
  float* dst = out + (size_t)row * L_;
  const int t = threadIdx.x;
  float vals[16];
  const float4* s4 = (const float4*)(src + t * 16);
#pragma unroll
  for (int i = 0; i < 4; i++) {
    float4 x = s4[i];
    vals[4 * i + 0] = x.x; vals[4 * i + 1] = x.y;
    vals[4 * i + 2] = x.z; vals[4 * i + 3] = x.w;
  }
  float run = 0.0f;
#pragma unroll
  for (int i = 0; i < 16; i++) { run += vals[i] * (1.0f / 64.0f); vals[i] = run; }
  float x = run;
#pragma unroll
  for (int off = 1; off < 64; off <<= 1) {
    float y = __shfl_up(x, off, 64);
    if ((t & 63) >= off) x += y;
  }
  __shared__ float wtot[4];
  if ((t & 63) == 63) wtot[t >> 6] = x;
  __syncthreads();
  float woff = 0.0f;
  for (int w = 0; w < (t >> 6); w++) woff += wtot[w];
  const float excl = x - run + woff;
#pragma unroll
  for (int i = 0; i < 16; i++) vals[i] += excl;
  float4* d4 = (float4*)(dst + t * 16);
#pragma unroll
  for (int i = 0; i < 4; i++)
    d4[i] = make_float4(vals[4 * i], vals[4 * i + 1], vals[4 * i + 2], vals[4 * i + 3]);
}

// ---------------- update phase 1: register-tiled GEMM per (bh, chunk-pair) ----------------
// XCD-swizzled: each XCD owns 4 bh (kraw/vt/qt slices stay L2-local).
__global__ __launch_bounds__(256) void update_partial(const float* __restrict__ qt,
                                                      const float* __restrict__ kraw,
                                                      const float* __restrict__ vt,
                                                      const int* __restrict__ ssel_g,
                                                      float* __restrict__ part) {
  const int xcd = blockIdx.x & 7;
  const int slot = blockIdx.x >> 3;   // 0..63
  const int bh = xcd * 4 + (slot >> 4);
  const int ch0 = slot & 15;
  const int t = threadIdx.x;
  const int w = t >> 6, lane = t & 63;
  const int kl = lane & 15, rg = lane >> 4;

  __shared__ float kv[CHUNK * 64];    // 32KB: kS[d][128] then vS[key][64]
  __shared__ float qs[48 * 68];       // padded stride 68
  __shared__ float eS[48 * 132];      // padded stride 132
  __shared__ int ssel[48];

  if (t < 48) ssel[t] = (t < TOPU) ? ssel_g[bh * TOPU + t] : -1;
  __syncthreads();

  // stage Q: 48 rows x 64 d (rows 45..47 zero)
#pragma unroll
  for (int j = 0; j < 3; j++) {
    int it = t + 256 * j;             // 0..767
    int rr = it >> 4, dc = it & 15;
    int sel = ssel[rr];
    float4 qv = make_float4(0.f, 0.f, 0.f, 0.f);
    if (sel >= 0) qv = *(const float4*)&qt[((size_t)bh * L_ + sel) * D_ + 4 * dc];
    *(float4*)&qs[rr * 68 + 4 * dc] = qv;
  }

  for (int pass = 0; pass < 2; pass++) {
    const int ch = pass ? (31 - ch0) : ch0;
    const int k0 = ch * CHUNK;
    int lo = 0, hi = TOPU;
    while (lo < hi) { int mid = (lo + hi) >> 1; if (ssel[mid] >= k0) lo = mid + 1; else hi = mid; }
    const int nact = lo;
    if (nact == 0) continue;          // uniform across block

    __syncthreads();
    // stage K: kv[d*128 + key] = kraw[bh, d, k0+key]
    const float* kb = kraw + (size_t)bh * D_ * L_ + k0;
#pragma unroll
    for (int j = 0; j < 8; j++) {
      int e4 = 4 * (t + 256 * j);
      int d = e4 >> 7, key = e4 & 127;
      *(float4*)&kv[e4] = *(const float4*)&kb[(size_t)d * L_ + key];
    }
    __syncthreads();

    const int wr0 = 12 * w;
    if (wr0 < nact) {
      float s[3][8];
#pragma unroll
      for (int j = 0; j < 3; j++)
#pragma unroll
        for (int x = 0; x < 8; x++) s[j][x] = 0.f;
#pragma unroll 8
      for (int d = 0; d < 64; d++) {
        float4 ka = *(const float4*)&kv[d * 128 + 4 * kl];
        float4 kb2 = *(const float4*)&kv[d * 128 + 64 + 4 * kl];
#pragma unroll
        for (int j = 0; j < 3; j++) {
          float qd = qs[(wr0 + 3 * rg + j) * 68 + d];
          s[j][0] += qd * ka.x;  s[j][1] += qd * ka.y;
          s[j][2] += qd * ka.z;  s[j][3] += qd * ka.w;
          s[j][4] += qd * kb2.x; s[j][5] += qd * kb2.y;
          s[j][6] += qd * kb2.z; s[j][7] += qd * kb2.w;
        }
      }
#pragma unroll
      for (int j = 0; j < 3; j++) {
        const int R = wr0 + 3 * rg + j;
        const int sel = ssel[R];
        float mx = -INFINITY;
#pragma unroll
        for (int x = 0; x < 8; x++) {
          int kg = k0 + 4 * kl + (x < 4 ? x : 60 + x);   // keys 4kl+{0..3}, 64+4kl+{0..3}
          s[j][x] *= (1.0f / 32768.0f);
          if (kg > sel) s[j][x] = -INFINITY;
          mx = fmaxf(mx, s[j][x]);
        }
        mx = fmaxf(mx, __shfl_xor(mx, 1, 64));
        mx = fmaxf(mx, __shfl_xor(mx, 2, 64));
        mx = fmaxf(mx, __shfl_xor(mx, 4, 64));
        mx = fmaxf(mx, __shfl_xor(mx, 8, 64));
        float e[8], sm = 0.f;
#pragma unroll
        for (int x = 0; x < 8; x++) { e[x] = expf(s[j][x] - mx); sm += e[x]; }
        sm += __shfl_xor(sm, 1, 64);
        sm += __shfl_xor(sm, 2, 64);
        sm += __shfl_xor(sm, 4, 64);
        sm += __shfl_xor(sm, 8, 64);
        *(float4*)&eS[R * 132 + 4 * kl] = make_float4(e[0], e[1], e[2], e[3]);
        *(float4*)&eS[R * 132 + 64 + 4 * kl] = make_float4(e[4], e[5], e[6], e[7]);
        if (kl == 0 && R < nact) {
          float* p = part + ((size_t)(bh * TOPU + R) * NCH + ch) * PSTRIDE;
          p[64] = mx; p[65] = sm;
        }
      }
    }
    __syncthreads();
    // stage V: kv[key*64 + d] = vt[bh, k0+key, d] (linear copy)
    const float* vb = vt + ((size_t)bh * L_ + k0) * D_;
#pragma unroll
    for (int j = 0; j < 8; j++) {
      int e4 = 4 * (t + 256 * j);
      *(float4*)&kv[e4] = *(const float4*)&vb[e4];
    }
    __syncthreads();
    if (wr0 < nact) {
      float acc[3][4];
#pragma unroll
      for (int j = 0; j < 3; j++)
#pragma unroll
        for (int x = 0; x < 4; x++) acc[j][x] = 0.f;
#pragma unroll 8
      for (int kp = 0; kp < 64; kp++) {
        float4 v0 = *(const float4*)&kv[(2 * kp) * 64 + 4 * kl];
        float4 v1 = *(const float4*)&kv[(2 * kp + 1) * 64 + 4 * kl];
#pragma unroll
        for (int j = 0; j < 3; j++) {
          float2 ee = *(const float2*)&eS[(wr0 + 3 * rg + j) * 132 + 2 * kp];
          acc[j][0] += ee.x * v0.x + ee.y * v1.x;
          acc[j][1] += ee.x * v0.y + ee.y * v1.y;
          acc[j][2] += ee.x * v0.z + ee.y * v1.z;
          acc[j][3] += ee.x * v0.w + ee.y * v1.w;
        }
      }
#pragma unroll
      for (int j = 0; j < 3; j++) {
        const int R = wr0 + 3 * rg + j;
        if (R < nact) {
          float* p = part + ((size_t)(bh * TOPU + R) * NCH + ch) * PSTRIDE;
          *(float4*)&p[4 * kl] = *(float4*)&acc[j][0];
        }
      }
    }
  }
}

// ---------------- update phase 2: combine valid chunks + write column ----------------
__global__ __launch_bounds__(64) void update_combine(const float* __restrict__ part,
                                                     const int* __restrict__ ssel_g,
                                                     float* __restrict__ out) {
  const int row = blockIdx.x;                 // 0..BH*TOPU-1 (sorted order)
  const int bh = row / TOPU;
  const int sel = ssel_g[row];
  const int d = threadIdx.x;                  // 0..63
  const int nv = sel / CHUNK + 1;             // valid chunks
  const float* p = part + (size_t)row * NCH * PSTRIDE;

  float m = -INFINITY;
  for (int c = 0; c < nv; c++) m = fmaxf(m, p[c * PSTRIDE + 64]);

  float num = 0.0f, den = 0.0f;
  for (int c = 0; c < nv; c++) {
    float mc = p[c * PSTRIDE + 64];
    float wgt = expf(mc - m);
    num += wgt * p[c * PSTRIDE + d];
    den += wgt * p[c * PSTRIDE + 65];
  }
  out[((size_t)bh * D_ + d) * L_ + sel] = num / den;
}

extern "C" void kernel_launch(void* const* d_in, const int* in_sizes, int n_in,
                              void* d_out, int out_size, void* d_ws, size_t ws_size,
                              hipStream_t stream) {
  const float* q = (const float*)d_in[0];
  const float* k = (const float*)d_in[1];
  const float* v = (const float*)d_in[2];
  float* out = (float*)d_out;

  const size_t NT = (size_t)BH * L_ * D_;     // 8388608 floats per tensor
  float* qt = (float*)d_ws;
  float* kt = qt + NT;
  float* vt = kt + NT;
  float* M  = vt + NT;                         // BH*L floats
  int* idx  = (int*)(M + (size_t)BH * L_);     // 4096*25 ints
  int* ssel = idx + L_ * U_PART;               // BH*45 ints (sorted desc per bh)
  float* part = (float*)(ssel + BH * TOPU);    // 1440*32*68 floats (~12.5 MB)

  uint32_t k2a, k2b;
#if JAX_THREEFRY_PARTITIONABLE
  tf2x32(0u, 42u, 0u, 1u, k2a, k2b);
#else
  uint32_t a0, a1, b0, b1;
  tf2x32(0u, 42u, 0u, 2u, a0, a1);
  tf2x32(0u, 42u, 1u, 3u, b0, b1);
  k2a = a1; k2b = b1;
#endif

  transpose_scale<<<dim3(L_ / 64, BH, 3), 256, 0, stream>>>(q, k, v, qt, kt, vt);
#if JAX_THREEFRY_PARTITIONABLE
  sample_idx_kernel<<<(L_ * U_PART + 255) / 256, 256, 0, stream>>>(idx, k2a, k2b);
#else
  sample_idx_kernel<<<(L_ * U_PART / 2 + 255) / 256, 256, 0, stream>>>(idx, k2a, k2b);
#endif
  m_kernel<<<BH * L_ / 64, 256, 0, stream>>>(qt, kt, idx, M);
  topk_kernel<<<BH, 256, 0, stream>>>(M, ssel);
  cumsum_kernel<<<BH * D_, 256, 0, stream>>>(v, out);
  update_partial<<<BH * 16, 256, 0, stream>>>(qt, k, vt, ssel, part);
  update_combine<<<BH * TOPU, 64, 0, stream>>>(part, ssel, out);
}

// Round 9
// 178.017 us; speedup vs baseline: 1.1486x; 1.1486x over previous
//
#include <hip/hip_runtime.h>
#include <cstdint>

// Reference geometry (fixed problem)
constexpr int B_ = 4, H_ = 8, D_ = 64, L_ = 4096;
constexpr int BH = B_ * H_;          // 32
constexpr int U_PART = 25;           // FACTOR * ceil(log(64))
constexpr int TOPU = 45;             // FACTOR * ceil(log(4096))
constexpr int CHUNK = 128;           // keys per update chunk (LDS-staged)
constexpr int NCH = L_ / CHUNK;      // 32 chunks
constexpr int PSTRIDE = 68;          // acc[64], max, sum, pad to 16B-aligned stride

#define JAX_THREEFRY_PARTITIONABLE 1

// ---------------- Threefry-2x32 (exact JAX semantics) ----------------
__host__ __device__ inline void tf2x32(uint32_t k0, uint32_t k1,
                                       uint32_t x0, uint32_t x1,
                                       uint32_t& y0, uint32_t& y1) {
  const uint32_t ks2 = k0 ^ k1 ^ 0x1BD11BDAu;
  uint32_t v0 = x0 + k0, v1 = x1 + k1;
#define RND(r) { v0 += v1; v1 = (v1 << (r)) | (v1 >> (32 - (r))); v1 ^= v0; }
  RND(13) RND(15) RND(26) RND(6)
  v0 += k1; v1 += ks2 + 1u;
  RND(17) RND(29) RND(16) RND(24)
  v0 += ks2; v1 += k0 + 2u;
  RND(13) RND(15) RND(26) RND(6)
  v0 += k0; v1 += k1 + 3u;
  RND(17) RND(29) RND(16) RND(24)
  v0 += k1; v1 += ks2 + 4u;
  RND(13) RND(15) RND(26) RND(6)
  v0 += ks2; v1 += k0 + 5u;
#undef RND
  y0 = v0; y1 = v1;
}

__global__ __launch_bounds__(256) void sample_idx_kernel(int* __restrict__ idx,
                                                         uint32_t k2a, uint32_t k2b) {
#if JAX_THREEFRY_PARTITIONABLE
  int i = blockIdx.x * 256 + threadIdx.x;
  if (i >= L_ * U_PART) return;
  uint32_t y0, y1;
  tf2x32(k2a, k2b, 0u, (uint32_t)i, y0, y1);
  idx[i] = (int)((y0 ^ y1) & 4095u);
#else
  int j = blockIdx.x * 256 + threadIdx.x;
  const int half = (L_ * U_PART) / 2;   // 51200
  if (j >= half) return;
  uint32_t y0, y1;
  tf2x32(k2a, k2b, (uint32_t)j, (uint32_t)(j + half), y0, y1);
  idx[j] = (int)(y0 & 4095u);
  idx[j + half] = (int)(y1 & 4095u);
#endif
}

// ---------------- Transpose + scale: (BH, D, L) -> (BH, L, D) ----------------
__global__ __launch_bounds__(256) void transpose_scale(
    const float* __restrict__ q, const float* __restrict__ k, const float* __restrict__ v,
    float* __restrict__ qt, float* __restrict__ kt, float* __restrict__ vt) {
  const float* src; float* dst; float scale;
  if (blockIdx.z == 0)      { src = q; dst = qt; scale = 1.0f / 512.0f; }
  else if (blockIdx.z == 1) { src = k; dst = kt; scale = 1.0f / 64.0f; }
  else                      { src = v; dst = vt; scale = 1.0f / 64.0f; }
  const int bh = blockIdx.y;
  const int l0 = blockIdx.x * 64;
  __shared__ float tile[64][65];
  const float* s = src + (size_t)bh * D_ * L_;
  float* d = dst + (size_t)bh * L_ * D_;
  const int t = threadIdx.x;
#pragma unroll
  for (int i = 0; i < 16; i++) {
    int li = i * 256 + t;          // 0..4095
    int dd = li >> 6, ll = li & 63;
    tile[dd][ll] = s[(size_t)dd * L_ + l0 + ll] * scale;
  }
  __syncthreads();
#pragma unroll
  for (int i = 0; i < 16; i++) {
    int li = i * 256 + t;
    int ll = li >> 6, dd = li & 63;
    d[(size_t)(l0 + ll) * D_ + dd] = tile[dd][ll];
  }
}

// ---------------- DPP 16-lane butterfly helper (VALU, no DS pipe) ----------------
// Covering involutions: row_mirror(0x140), row_half_mirror(0x141),
// quad_perm[2,3,0,1](0x4E), quad_perm[1,0,3,2](0xB1). After all 4 steps every
// lane of each 16-lane row holds the full reduction.
__device__ __forceinline__ float dpp_bcast_add16(float x) {
  int xi;
  xi = __builtin_amdgcn_mov_dpp(__float_as_int(x), 0x140, 0xF, 0xF, true);
  x += __int_as_float(xi);
  xi = __builtin_amdgcn_mov_dpp(__float_as_int(x), 0x141, 0xF, 0xF, true);
  x += __int_as_float(xi);
  xi = __builtin_amdgcn_mov_dpp(__float_as_int(x), 0x4E, 0xF, 0xF, true);
  x += __int_as_float(xi);
  xi = __builtin_amdgcn_mov_dpp(__float_as_int(x), 0xB1, 0xF, 0xF, true);
  x += __int_as_float(xi);
  return x;
}

// ---------------- M[b,h,l] = max_s QK - sum_s QK / 4096 ----------------
// 16 lanes per l (float4 fragments) -> per wave-instruction the gather is
// 4 contiguous 256B segments (proven-good VMEM shape, r7: 47us).
// Reduction via DPP (VALU) instead of shfl (DS pipe).
// XCD-swizzled: each XCD owns 4 bh (kt stays L2-resident).
__global__ __launch_bounds__(256) void m_kernel(const float* __restrict__ qt,
                                                const float* __restrict__ kt,
                                                const int* __restrict__ idx,
                                                float* __restrict__ M) {
  const int t = threadIdx.x;
  const int w = t >> 6, lane = t & 63;
  const int g = lane >> 4, gl = lane & 15;     // group in wave, lane in group
  const int xcd = blockIdx.x & 7;              // blockIdx%8 = XCD [m09]
  const int slot = blockIdx.x >> 3;            // 0..1023
  const int bh = xcd * 4 + (slot >> 8);
  const int lg = slot & 255;
  const int l = lg * 16 + w * 4 + g;
  const int gidx = bh * L_ + l;
  const float* qtb = qt + (size_t)bh * L_ * D_;
  const float* ktb = kt + (size_t)bh * L_ * D_;
  const float4 ql = *(const float4*)(qtb + (size_t)l * D_ + gl * 4);
  const int* ip = idx + l * U_PART;
  float mx = -INFINITY, sm = 0.0f;
#pragma unroll 5
  for (int s = 0; s < U_PART; s++) {
    int ki = ip[s];
    float4 kk = *(const float4*)(ktb + (size_t)ki * D_ + gl * 4);
    float p = ql.x * kk.x + ql.y * kk.y + ql.z * kk.z + ql.w * kk.w;
    p = dpp_bcast_add16(p);
    mx = fmaxf(mx, p);
    sm += p;
  }
  if (gl == 0) M[gidx] = mx - sm * (1.0f / 4096.0f);
}

// ---------------- top-45 per (b,h), register-resident, SORTED DESC by index ----------------
__global__ __launch_bounds__(256) void topk_kernel(const float* __restrict__ M,
                                                   int* __restrict__ ssel_g) {
  const int bh = blockIdx.x, t = threadIdx.x;
  const int w = t >> 6, lane = t & 63;
  const float* Mb = M + (size_t)bh * L_;
  const int base = w * 1024 + lane;
  uint32_t v[16];
#pragma unroll
  for (int j = 0; j < 16; j++) {          // coalesced: lanes read consecutive
    uint32_t b = __float_as_uint(Mb[base + j * 64]);
    v[j] = b ^ ((b & 0x80000000u) ? 0xFFFFFFFFu : 0x80000000u);
  }
  __shared__ unsigned long long red[4];
  __shared__ int picks[TOPU];
  for (int it = 0; it < TOPU; it++) {
    unsigned long long best = 0ull;
#pragma unroll
    for (int j = 0; j < 16; j++) {
      unsigned long long key = ((unsigned long long)v[j] << 32)
                             | (uint32_t)(L_ - 1 - (base + j * 64));
      best = (key > best) ? key : best;
    }
#pragma unroll
    for (int off = 32; off; off >>= 1) {
      unsigned long long o = __shfl_xor(best, off, 64);
      best = (o > best) ? o : best;
    }
    if (lane == 0) red[w] = best;
    __syncthreads();
    unsigned long long g = red[0];
    if (red[1] > g) g = red[1];
    if (red[2] > g) g = red[2];
    if (red[3] > g) g = red[3];
    const int bi = L_ - 1 - (int)(g & 0xFFFFFFFFu);
    if (t == 0) picks[it] = bi;
    if ((bi >> 10) == w && (bi & 63) == lane) {   // remove winner
      const int slot = (bi >> 6) & 15;
#pragma unroll
      for (int j = 0; j < 16; j++) if (slot == j) v[j] = 0u;
    }
    __syncthreads();
  }
  // rank-sort descending by key index (indices distinct)
  if (t < TOPU) {
    int my = picks[t];
    int rank = 0;
    for (int j = 0; j < TOPU; j++) rank += (picks[j] > my);
    ssel_g[bh * TOPU + rank] = my;
  }
}

// ---------------- out[bh,d,l] = cumsum_l v[bh,d,l] / 64 ----------------
__global__ __launch_bounds__(256) void cumsum_kernel(const float* __restrict__ v,
                                                     float* __restrict__ out) {
  const int row = blockIdx.x;                 // BH*D rows
  const float* src = v + (size_t)row * L_;
  float* dst = out + (size_t)row * L_;
  const int t = threadIdx.x;
  float vals[16];
  const float4* s4 = (const float4*)(src + t * 16);
#pragma unroll
  for (int i = 0; i < 4; i++) {
    float4 x = s4[i];
    vals[4 * i + 0] = x.x; vals[4 * i + 1] = x.y;
    vals[4 * i + 2] = x.z; vals[4 * i + 3] = x.w;
  }
  float run = 0.0f;
#pragma unroll
  for (int i = 0; i < 16; i++) { run += vals[i] * (1.0f / 64.0f); vals[i] = run; }
  float x = run;
#pragma unroll
  for (int off = 1; off < 64; off <<= 1) {
    float y = __shfl_up(x, off, 64);
    if ((t & 63) >= off) x += y;
  }
  __shared__ float wtot[4];
  if ((t & 63) == 63) wtot[t >> 6] = x;
  __syncthreads();
  float woff = 0.0f;
  for (int w = 0; w < (t >> 6); w++) woff += wtot[w];
  const float excl = x - run + woff;
#pragma unroll
  for (int i = 0; i < 16; i++) vals[i] += excl;
  float4* d4 = (float4*)(dst + t * 16);
#pragma unroll
  for (int i = 0; i < 4; i++)
    d4[i] = make_float4(vals[4 * i], vals[4 * i + 1], vals[4 * i + 2], vals[4 * i + 3]);
}

// ---------------- update phase 1: register-tiled GEMM per (bh, chunk-pair) ----------------
// XCD-swizzled: each XCD owns 4 bh (kraw/vt/qt slices stay L2-local).
__global__ __launch_bounds__(256) void update_partial(const float* __restrict__ qt,
                                                      const float* __restrict__ kraw,
                                                      const float* __restrict__ vt,
                                                      const int* __restrict__ ssel_g,
                                                      float* __restrict__ part) {
  const int xcd = blockIdx.x & 7;
  const int slot = blockIdx.x >> 3;   // 0..63
  const int bh = xcd * 4 + (slot >> 4);
  const int ch0 = slot & 15;
  const int t = threadIdx.x;
  const int w = t >> 6, lane = t & 63;
  const int kl = lane & 15, rg = lane >> 4;

  __shared__ float kv[CHUNK * 64];    // 32KB: kS[d][128] then vS[key][64]
  __shared__ float qs[48 * 68];       // padded stride 68
  __shared__ float eS[48 * 132];      // padded stride 132
  __shared__ int ssel[48];

  if (t < 48) ssel[t] = (t < TOPU) ? ssel_g[bh * TOPU + t] : -1;
  __syncthreads();

  // stage Q: 48 rows x 64 d (rows 45..47 zero)
#pragma unroll
  for (int j = 0; j < 3; j++) {
    int it = t + 256 * j;             // 0..767
    int rr = it >> 4, dc = it & 15;
    int sel = ssel[rr];
    float4 qv = make_float4(0.f, 0.f, 0.f, 0.f);
    if (sel >= 0) qv = *(const float4*)&qt[((size_t)bh * L_ + sel) * D_ + 4 * dc];
    *(float4*)&qs[rr * 68 + 4 * dc] = qv;
  }

  for (int pass = 0; pass < 2; pass++) {
    const int ch = pass ? (31 - ch0) : ch0;
    const int k0 = ch * CHUNK;
    int lo = 0, hi = TOPU;
    while (lo < hi) { int mid = (lo + hi) >> 1; if (ssel[mid] >= k0) lo = mid + 1; else hi = mid; }
    const int nact = lo;
    if (nact == 0) continue;          // uniform across block

    __syncthreads();
    // stage K: kv[d*128 + key] = kraw[bh, d, k0+key]
    const float* kb = kraw + (size_t)bh * D_ * L_ + k0;
#pragma unroll
    for (int j = 0; j < 8; j++) {
      int e4 = 4 * (t + 256 * j);
      int d = e4 >> 7, key = e4 & 127;
      *(float4*)&kv[e4] = *(const float4*)&kb[(size_t)d * L_ + key];
    }
    __syncthreads();

    const int wr0 = 12 * w;
    if (wr0 < nact) {
      float s[3][8];
#pragma unroll
      for (int j = 0; j < 3; j++)
#pragma unroll
        for (int x = 0; x < 8; x++) s[j][x] = 0.f;
#pragma unroll 8
      for (int d = 0; d < 64; d++) {
        float4 ka = *(const float4*)&kv[d * 128 + 4 * kl];
        float4 kb2 = *(const float4*)&kv[d * 128 + 64 + 4 * kl];
#pragma unroll
        for (int j = 0; j < 3; j++) {
          float qd = qs[(wr0 + 3 * rg + j) * 68 + d];
          s[j][0] += qd * ka.x;  s[j][1] += qd * ka.y;
          s[j][2] += qd * ka.z;  s[j][3] += qd * ka.w;
          s[j][4] += qd * kb2.x; s[j][5] += qd * kb2.y;
          s[j][6] += qd * kb2.z; s[j][7] += qd * kb2.w;
        }
      }
#pragma unroll
      for (int j = 0; j < 3; j++) {
        const int R = wr0 + 3 * rg + j;
        const int sel = ssel[R];
        float mx = -INFINITY;
#pragma unroll
        for (int x = 0; x < 8; x++) {
          int kg = k0 + 4 * kl + (x < 4 ? x : 60 + x);   // keys 4kl+{0..3}, 64+4kl+{0..3}
          s[j][x] *= (1.0f / 32768.0f);
          if (kg > sel) s[j][x] = -INFINITY;
          mx = fmaxf(mx, s[j][x]);
        }
        mx = fmaxf(mx, __shfl_xor(mx, 1, 64));
        mx = fmaxf(mx, __shfl_xor(mx, 2, 64));
        mx = fmaxf(mx, __shfl_xor(mx, 4, 64));
        mx = fmaxf(mx, __shfl_xor(mx, 8, 64));
        float e[8], sm = 0.f;
#pragma unroll
        for (int x = 0; x < 8; x++) { e[x] = expf(s[j][x] - mx); sm += e[x]; }
        sm += __shfl_xor(sm, 1, 64);
        sm += __shfl_xor(sm, 2, 64);
        sm += __shfl_xor(sm, 4, 64);
        sm += __shfl_xor(sm, 8, 64);
        *(float4*)&eS[R * 132 + 4 * kl] = make_float4(e[0], e[1], e[2], e[3]);
        *(float4*)&eS[R * 132 + 64 + 4 * kl] = make_float4(e[4], e[5], e[6], e[7]);
        if (kl == 0 && R < nact) {
          float* p = part + ((size_t)(bh * TOPU + R) * NCH + ch) * PSTRIDE;
          p[64] = mx; p[65] = sm;
        }
      }
    }
    __syncthreads();
    // stage V: kv[key*64 + d] = vt[bh, k0+key, d] (linear copy)
    const float* vb = vt + ((size_t)bh * L_ + k0) * D_;
#pragma unroll
    for (int j = 0; j < 8; j++) {
      int e4 = 4 * (t + 256 * j);
      *(float4*)&kv[e4] = *(const float4*)&vb[e4];
    }
    __syncthreads();
    if (wr0 < nact) {
      float acc[3][4];
#pragma unroll
      for (int j = 0; j < 3; j++)
#pragma unroll
        for (int x = 0; x < 4; x++) acc[j][x] = 0.f;
#pragma unroll 8
      for (int kp = 0; kp < 64; kp++) {
        float4 v0 = *(const float4*)&kv[(2 * kp) * 64 + 4 * kl];
        float4 v1 = *(const float4*)&kv[(2 * kp + 1) * 64 + 4 * kl];
#pragma unroll
        for (int j = 0; j < 3; j++) {
          float2 ee = *(const float2*)&eS[(wr0 + 3 * rg + j) * 132 + 2 * kp];
          acc[j][0] += ee.x * v0.x + ee.y * v1.x;
          acc[j][1] += ee.x * v0.y + ee.y * v1.y;
          acc[j][2] += ee.x * v0.z + ee.y * v1.z;
          acc[j][3] += ee.x * v0.w + ee.y * v1.w;
        }
      }
#pragma unroll
      for (int j = 0; j < 3; j++) {
        const int R = wr0 + 3 * rg + j;
        if (R < nact) {
          float* p = part + ((size_t)(bh * TOPU + R) * NCH + ch) * PSTRIDE;
          *(float4*)&p[4 * kl] = *(float4*)&acc[j][0];
        }
      }
    }
  }
}

// ---------------- update phase 2: combine valid chunks + write column ----------------
__global__ __launch_bounds__(64) void update_combine(const float* __restrict__ part,
                                                     const int* __restrict__ ssel_g,
                                                     float* __restrict__ out) {
  const int row = blockIdx.x;                 // 0..BH*TOPU-1 (sorted order)
  const int bh = row / TOPU;
  const int sel = ssel_g[row];
  const int d = threadIdx.x;                  // 0..63
  const int nv = sel / CHUNK + 1;             // valid chunks
  const float* p = part + (size_t)row * NCH * PSTRIDE;

  float m = -INFINITY;
  for (int c = 0; c < nv; c++) m = fmaxf(m, p[c * PSTRIDE + 64]);

  float num = 0.0f, den = 0.0f;
  for (int c = 0; c < nv; c++) {
    float mc = p[c * PSTRIDE + 64];
    float wgt = expf(mc - m);
    num += wgt * p[c * PSTRIDE + d];
    den += wgt * p[c * PSTRIDE + 65];
  }
  out[((size_t)bh * D_ + d) * L_ + sel] = num / den;
}

extern "C" void kernel_launch(void* const* d_in, const int* in_sizes, int n_in,
                              void* d_out, int out_size, void* d_ws, size_t ws_size,
                              hipStream_t stream) {
  const float* q = (const float*)d_in[0];
  const float* k = (const float*)d_in[1];
  const float* v = (const float*)d_in[2];
  float* out = (float*)d_out;

  const size_t NT = (size_t)BH * L_ * D_;     // 8388608 floats per tensor
  float* qt = (float*)d_ws;
  float* kt = qt + NT;
  float* vt = kt + NT;
  float* M  = vt + NT;                         // BH*L floats
  int* idx  = (int*)(M + (size_t)BH * L_);     // 4096*25 ints
  int* ssel = idx + L_ * U_PART;               // BH*45 ints (sorted desc per bh)
  float* part = (float*)(ssel + BH * TOPU);    // 1440*32*68 floats (~12.5 MB)

  uint32_t k2a, k2b;
#if JAX_THREEFRY_PARTITIONABLE
  tf2x32(0u, 42u, 0u, 1u, k2a, k2b);
#else
  uint32_t a0, a1, b0, b1;
  tf2x32(0u, 42u, 0u, 2u, a0, a1);
  tf2x32(0u, 42u, 1u, 3u, b0, b1);
  k2a = a1; k2b = b1;
#endif

  transpose_scale<<<dim3(L_ / 64, BH, 3), 256, 0, stream>>>(q, k, v, qt, kt, vt);
#if JAX_THREEFRY_PARTITIONABLE
  sample_idx_kernel<<<(L_ * U_PART + 255) / 256, 256, 0, stream>>>(idx, k2a, k2b);
#else
  sample_idx_kernel<<<(L_ * U_PART / 2 + 255) / 256, 256, 0, stream>>>(idx, k2a, k2b);
#endif
  m_kernel<<<BH * L_ / 16, 256, 0, stream>>>(qt, kt, idx, M);
  topk_kernel<<<BH, 256, 0, stream>>>(M, ssel);
  cumsum_kernel<<<BH * D_, 256, 0, stream>>>(v, out);
  update_partial<<<BH * 16, 256, 0, stream>>>(qt, k, vt, ssel, part);
  update_combine<<<BH * TOPU, 64, 0, stream>>>(part, ssel, out);
}

// Round 10
// 170.127 us; speedup vs baseline: 1.2018x; 1.0464x over previous
//
#include <hip/hip_runtime.h>
#include <cstdint>

// Reference geometry (fixed problem)
constexpr int B_ = 4, H_ = 8, D_ = 64, L_ = 4096;
constexpr int BH = B_ * H_;          // 32
constexpr int U_PART = 25;           // FACTOR * ceil(log(64))
constexpr int TOPU = 45;             // FACTOR * ceil(log(4096))
constexpr int CHUNK = 128;           // keys per update chunk (LDS-staged)
constexpr int NCH = L_ / CHUNK;      // 32 chunks
constexpr int PSTRIDE = 68;          // acc[64], max, sum, pad to 16B-aligned stride

#define JAX_THREEFRY_PARTITIONABLE 1

// ---------------- Threefry-2x32 (exact JAX semantics) ----------------
__host__ __device__ inline void tf2x32(uint32_t k0, uint32_t k1,
                                       uint32_t x0, uint32_t x1,
                                       uint32_t& y0, uint32_t& y1) {
  const uint32_t ks2 = k0 ^ k1 ^ 0x1BD11BDAu;
  uint32_t v0 = x0 + k0, v1 = x1 + k1;
#define RND(r) { v0 += v1; v1 = (v1 << (r)) | (v1 >> (32 - (r))); v1 ^= v0; }
  RND(13) RND(15) RND(26) RND(6)
  v0 += k1; v1 += ks2 + 1u;
  RND(17) RND(29) RND(16) RND(24)
  v0 += ks2; v1 += k0 + 2u;
  RND(13) RND(15) RND(26) RND(6)
  v0 += k0; v1 += k1 + 3u;
  RND(17) RND(29) RND(16) RND(24)
  v0 += k1; v1 += ks2 + 4u;
  RND(13) RND(15) RND(26) RND(6)
  v0 += ks2; v1 += k0 + 5u;
#undef RND
  y0 = v0; y1 = v1;
}

__global__ __launch_bounds__(256) void sample_idx_kernel(int* __restrict__ idx,
                                                         uint32_t k2a, uint32_t k2b) {
#if JAX_THREEFRY_PARTITIONABLE
  int i = blockIdx.x * 256 + threadIdx.x;
  if (i >= L_ * U_PART) return;
  uint32_t y0, y1;
  tf2x32(k2a, k2b, 0u, (uint32_t)i, y0, y1);
  idx[i] = (int)((y0 ^ y1) & 4095u);
#else
  int j = blockIdx.x * 256 + threadIdx.x;
  const int half = (L_ * U_PART) / 2;   // 51200
  if (j >= half) return;
  uint32_t y0, y1;
  tf2x32(k2a, k2b, (uint32_t)j, (uint32_t)(j + half), y0, y1);
  idx[j] = (int)(y0 & 4095u);
  idx[j + half] = (int)(y1 & 4095u);
#endif
}

// ---------------- Fused: q/k transpose+scale (z=0,1) and v cumsum (z=2) ----------------
__global__ __launch_bounds__(256) void transpose_cumsum(
    const float* __restrict__ q, const float* __restrict__ k, const float* __restrict__ v,
    float* __restrict__ qt, float* __restrict__ kt, float* __restrict__ out) {
  const int bh = blockIdx.y;
  const int t = threadIdx.x;
  if (blockIdx.z == 2) {
    // cumsum of v/64 along L for row (bh, d=blockIdx.x)
    const int row = bh * D_ + blockIdx.x;
    const float* src = v + (size_t)row * L_;
    float* dst = out + (size_t)row * L_;
    float vals[16];
    const float4* s4 = (const float4*)(src + t * 16);
#pragma unroll
    for (int i = 0; i < 4; i++) {
      float4 x = s4[i];
      vals[4 * i + 0] = x.x; vals[4 * i + 1] = x.y;
      vals[4 * i + 2] = x.z; vals[4 * i + 3] = x.w;
    }
    float run = 0.0f;
#pragma unroll
    for (int i = 0; i < 16; i++) { run += vals[i] * (1.0f / 64.0f); vals[i] = run; }
    float x = run;
#pragma unroll
    for (int off = 1; off < 64; off <<= 1) {
      float y = __shfl_up(x, off, 64);
      if ((t & 63) >= off) x += y;
    }
    __shared__ float wtot[4];
    if ((t & 63) == 63) wtot[t >> 6] = x;
    __syncthreads();
    float woff = 0.0f;
    for (int w = 0; w < (t >> 6); w++) woff += wtot[w];
    const float excl = x - run + woff;
#pragma unroll
    for (int i = 0; i < 16; i++) vals[i] += excl;
    float4* d4 = (float4*)(dst + t * 16);
#pragma unroll
    for (int i = 0; i < 4; i++)
      d4[i] = make_float4(vals[4 * i], vals[4 * i + 1], vals[4 * i + 2], vals[4 * i + 3]);
    return;
  }
  // transpose + scale
  const float* src; float* dst; float scale;
  if (blockIdx.z == 0) { src = q; dst = qt; scale = 1.0f / 512.0f; }
  else                 { src = k; dst = kt; scale = 1.0f / 64.0f; }
  const int l0 = blockIdx.x * 64;
  __shared__ float tile[64][65];
  const float* s = src + (size_t)bh * D_ * L_;
  float* d = dst + (size_t)bh * L_ * D_;
#pragma unroll
  for (int i = 0; i < 16; i++) {
    int li = i * 256 + t;          // 0..4095
    int dd = li >> 6, ll = li & 63;
    tile[dd][ll] = s[(size_t)dd * L_ + l0 + ll] * scale;
  }
  __syncthreads();
#pragma unroll
  for (int i = 0; i < 16; i++) {
    int li = i * 256 + t;
    int ll = li >> 6, dd = li & 63;
    d[(size_t)(l0 + ll) * D_ + dd] = tile[dd][ll];
  }
}

// ---------------- DPP 16-lane butterfly helper (VALU, no DS pipe) ----------------
__device__ __forceinline__ float dpp_bcast_add16(float x) {
  int xi;
  xi = __builtin_amdgcn_mov_dpp(__float_as_int(x), 0x140, 0xF, 0xF, true);
  x += __int_as_float(xi);
  xi = __builtin_amdgcn_mov_dpp(__float_as_int(x), 0x141, 0xF, 0xF, true);
  x += __int_as_float(xi);
  xi = __builtin_amdgcn_mov_dpp(__float_as_int(x), 0x4E, 0xF, 0xF, true);
  x += __int_as_float(xi);
  xi = __builtin_amdgcn_mov_dpp(__float_as_int(x), 0xB1, 0xF, 0xF, true);
  x += __int_as_float(xi);
  return x;
}

// ---------------- M[b,h,l] = max_s QK - sum_s QK / 4096 ----------------
// 16 lanes per l; DPP reduce; XCD-swizzled (each XCD owns 4 bh).
__global__ __launch_bounds__(256) void m_kernel(const float* __restrict__ qt,
                                                const float* __restrict__ kt,
                                                const int* __restrict__ idx,
                                                float* __restrict__ M) {
  const int t = threadIdx.x;
  const int w = t >> 6, lane = t & 63;
  const int g = lane >> 4, gl = lane & 15;
  const int xcd = blockIdx.x & 7;
  const int slot = blockIdx.x >> 3;            // 0..1023
  const int bh = xcd * 4 + (slot >> 8);
  const int lg = slot & 255;
  const int l = lg * 16 + w * 4 + g;
  const int gidx = bh * L_ + l;
  const float* qtb = qt + (size_t)bh * L_ * D_;
  const float* ktb = kt + (size_t)bh * L_ * D_;
  const float4 ql = *(const float4*)(qtb + (size_t)l * D_ + gl * 4);
  const int* ip = idx + l * U_PART;
  float mx = -INFINITY, sm = 0.0f;
#pragma unroll 5
  for (int s = 0; s < U_PART; s++) {
    int ki = ip[s];
    float4 kk = *(const float4*)(ktb + (size_t)ki * D_ + gl * 4);
    float p = ql.x * kk.x + ql.y * kk.y + ql.z * kk.z + ql.w * kk.w;
    p = dpp_bcast_add16(p);
    mx = fmaxf(mx, p);
    sm += p;
  }
  if (gl == 0) M[gidx] = mx - sm * (1.0f / 4096.0f);
}

// ---------------- top-45 per (b,h), register-resident, SORTED DESC by index ----------------
__global__ __launch_bounds__(256) void topk_kernel(const float* __restrict__ M,
                                                   int* __restrict__ ssel_g) {
  const int bh = blockIdx.x, t = threadIdx.x;
  const int w = t >> 6, lane = t & 63;
  const float* Mb = M + (size_t)bh * L_;
  const int base = w * 1024 + lane;
  uint32_t v[16];
#pragma unroll
  for (int j = 0; j < 16; j++) {
    uint32_t b = __float_as_uint(Mb[base + j * 64]);
    v[j] = b ^ ((b & 0x80000000u) ? 0xFFFFFFFFu : 0x80000000u);
  }
  __shared__ unsigned long long red[4];
  __shared__ int picks[TOPU];
  for (int it = 0; it < TOPU; it++) {
    unsigned long long best = 0ull;
#pragma unroll
    for (int j = 0; j < 16; j++) {
      unsigned long long key = ((unsigned long long)v[j] << 32)
                             | (uint32_t)(L_ - 1 - (base + j * 64));
      best = (key > best) ? key : best;
    }
#pragma unroll
    for (int off = 32; off; off >>= 1) {
      unsigned long long o = __shfl_xor(best, off, 64);
      best = (o > best) ? o : best;
    }
    if (lane == 0) red[w] = best;
    __syncthreads();
    unsigned long long g = red[0];
    if (red[1] > g) g = red[1];
    if (red[2] > g) g = red[2];
    if (red[3] > g) g = red[3];
    const int bi = L_ - 1 - (int)(g & 0xFFFFFFFFu);
    if (t == 0) picks[it] = bi;
    if ((bi >> 10) == w && (bi & 63) == lane) {
      const int slot = (bi >> 6) & 15;
#pragma unroll
      for (int j = 0; j < 16; j++) if (slot == j) v[j] = 0u;
    }
    __syncthreads();
  }
  if (t < TOPU) {
    int my = picks[t];
    int rank = 0;
    for (int j = 0; j < TOPU; j++) rank += (picks[j] > my);
    ssel_g[bh * TOPU + rank] = my;
  }
}

// ---------------- update phase 1: register-tiled GEMM per (bh, chunk-pair) ----------------
// K staged linear [d][key] from raw k; V staged [d][key] with granule-XOR swizzle
// from raw v (no vt transpose needed). PV dots along the key axis. XCD-swizzled.
__global__ __launch_bounds__(256) void update_partial(const float* __restrict__ qt,
                                                      const float* __restrict__ kraw,
                                                      const float* __restrict__ vraw,
                                                      const int* __restrict__ ssel_g,
                                                      float* __restrict__ part) {
  const int xcd = blockIdx.x & 7;
  const int slot = blockIdx.x >> 3;   // 0..63
  const int bh = xcd * 4 + (slot >> 4);
  const int ch0 = slot & 15;
  const int t = threadIdx.x;
  const int w = t >> 6, lane = t & 63;
  const int kl = lane & 15, rg = lane >> 4;

  __shared__ float kv[CHUNK * 64];    // 32KB: kS[d][128] linear, then vS[d][128] swizzled
  __shared__ float qs[48 * 68];       // padded stride 68
  __shared__ float eS[48 * 132];      // padded stride 132
  __shared__ int ssel[48];

  if (t < 48) ssel[t] = (t < TOPU) ? ssel_g[bh * TOPU + t] : -1;
  __syncthreads();

  // stage Q: 48 rows x 64 d (rows 45..47 zero)
#pragma unroll
  for (int j = 0; j < 3; j++) {
    int it = t + 256 * j;             // 0..767
    int rr = it >> 4, dc = it & 15;
    int sel = ssel[rr];
    float4 qv = make_float4(0.f, 0.f, 0.f, 0.f);
    if (sel >= 0) qv = *(const float4*)&qt[((size_t)bh * L_ + sel) * D_ + 4 * dc];
    *(float4*)&qs[rr * 68 + 4 * dc] = qv;
  }

  for (int pass = 0; pass < 2; pass++) {
    const int ch = pass ? (31 - ch0) : ch0;
    const int k0 = ch * CHUNK;
    int lo = 0, hi = TOPU;
    while (lo < hi) { int mid = (lo + hi) >> 1; if (ssel[mid] >= k0) lo = mid + 1; else hi = mid; }
    const int nact = lo;
    if (nact == 0) continue;          // uniform across block

    __syncthreads();
    // stage K: kv[d*128 + key] = kraw[bh, d, k0+key]  (linear, conflict-free)
    const float* kb = kraw + (size_t)bh * D_ * L_ + k0;
#pragma unroll
    for (int j = 0; j < 8; j++) {
      int e4 = 4 * (t + 256 * j);
      int d = e4 >> 7, key = e4 & 127;
      *(float4*)&kv[e4] = *(const float4*)&kb[(size_t)d * L_ + key];
    }
    __syncthreads();

    const int wr0 = 12 * w;
    if (wr0 < nact) {
      float s[3][8];
#pragma unroll
      for (int j = 0; j < 3; j++)
#pragma unroll
        for (int x = 0; x < 8; x++) s[j][x] = 0.f;
#pragma unroll 8
      for (int d = 0; d < 64; d++) {
        float4 ka = *(const float4*)&kv[d * 128 + 4 * kl];
        float4 kb2 = *(const float4*)&kv[d * 128 + 64 + 4 * kl];
#pragma unroll
        for (int j = 0; j < 3; j++) {
          float qd = qs[(wr0 + 3 * rg + j) * 68 + d];
          s[j][0] += qd * ka.x;  s[j][1] += qd * ka.y;
          s[j][2] += qd * ka.z;  s[j][3] += qd * ka.w;
          s[j][4] += qd * kb2.x; s[j][5] += qd * kb2.y;
          s[j][6] += qd * kb2.z; s[j][7] += qd * kb2.w;
        }
      }
#pragma unroll
      for (int j = 0; j < 3; j++) {
        const int R = wr0 + 3 * rg + j;
        const int sel = ssel[R];
        float mx = -INFINITY;
#pragma unroll
        for (int x = 0; x < 8; x++) {
          int kg = k0 + 4 * kl + (x < 4 ? x : 60 + x);   // keys 4kl+{0..3}, 64+4kl+{0..3}
          s[j][x] *= (1.0f / 32768.0f);
          if (kg > sel) s[j][x] = -INFINITY;
          mx = fmaxf(mx, s[j][x]);
        }
        mx = fmaxf(mx, __shfl_xor(mx, 1, 64));
        mx = fmaxf(mx, __shfl_xor(mx, 2, 64));
        mx = fmaxf(mx, __shfl_xor(mx, 4, 64));
        mx = fmaxf(mx, __shfl_xor(mx, 8, 64));
        float e[8], sm = 0.f;
#pragma unroll
        for (int x = 0; x < 8; x++) { e[x] = expf(s[j][x] - mx); sm += e[x]; }
        sm += __shfl_xor(sm, 1, 64);
        sm += __shfl_xor(sm, 2, 64);
        sm += __shfl_xor(sm, 4, 64);
        sm += __shfl_xor(sm, 8, 64);
        *(float4*)&eS[R * 132 + 4 * kl] = make_float4(e[0], e[1], e[2], e[3]);
        *(float4*)&eS[R * 132 + 64 + 4 * kl] = make_float4(e[4], e[5], e[6], e[7]);
        if (kl == 0 && R < nact) {
          float* p = part + ((size_t)(bh * TOPU + R) * NCH + ch) * PSTRIDE;
          p[64] = mx; p[65] = sm;
        }
      }
    }
    __syncthreads();
    // stage V: kv[d*128 + ((kq ^ (d&31))<<2)] = vraw[bh, d, k0+4kq..+3]
    // (linear-permuted granules per lane -> conflict-free b128 writes)
    const float* vb = vraw + (size_t)bh * D_ * L_ + k0;
#pragma unroll
    for (int j = 0; j < 8; j++) {
      int e4 = 4 * (t + 256 * j);
      int d = e4 >> 7, kq = (e4 & 127) >> 2;
      float4 vv = *(const float4*)&vb[(size_t)d * L_ + 4 * kq];
      *(float4*)&kv[d * 128 + ((kq ^ (d & 31)) << 2)] = vv;
    }
    __syncthreads();
    if (wr0 < nact) {
      float acc[3][4];
#pragma unroll
      for (int j = 0; j < 3; j++)
#pragma unroll
        for (int x = 0; x < 4; x++) acc[j][x] = 0.f;
      const int dbase = 4 * kl;
#pragma unroll 4
      for (int kb = 0; kb < 32; kb++) {
        float4 ev[3];
#pragma unroll
        for (int j = 0; j < 3; j++)
          ev[j] = *(const float4*)&eS[(wr0 + 3 * rg + j) * 132 + 4 * kb];
#pragma unroll
        for (int x = 0; x < 4; x++) {
          const int dx = dbase + x;
          float4 vv = *(const float4*)&kv[dx * 128 + ((kb ^ (dx & 31)) << 2)];
#pragma unroll
          for (int j = 0; j < 3; j++) {
            acc[j][x] += ev[j].x * vv.x + ev[j].y * vv.y
                       + ev[j].z * vv.z + ev[j].w * vv.w;
          }
        }
      }
#pragma unroll
      for (int j = 0; j < 3; j++) {
        const int R = wr0 + 3 * rg + j;
        if (R < nact) {
          float* p = part + ((size_t)(bh * TOPU + R) * NCH + ch) * PSTRIDE;
          float4 o = make_float4(acc[j][0] * (1.0f / 64.0f), acc[j][1] * (1.0f / 64.0f),
                                 acc[j][2] * (1.0f / 64.0f), acc[j][3] * (1.0f / 64.0f));
          *(float4*)&p[4 * kl] = o;
        }
      }
    }
  }
}

// ---------------- update phase 2: combine valid chunks + write column ----------------
// 256 threads = 4 waves, one row per wave.
__global__ __launch_bounds__(256) void update_combine(const float* __restrict__ part,
                                                      const int* __restrict__ ssel_g,
                                                      float* __restrict__ out) {
  const int row = blockIdx.x * 4 + (threadIdx.x >> 6);   // 0..BH*TOPU-1
  if (row >= BH * TOPU) return;
  const int bh = row / TOPU;
  const int sel = ssel_g[row];
  const int d = threadIdx.x & 63;
  const int nv = sel / CHUNK + 1;
  const float* p = part + (size_t)row * NCH * PSTRIDE;

  float m = -INFINITY;
  for (int c = 0; c < nv; c++) m = fmaxf(m, p[c * PSTRIDE + 64]);

  float num = 0.0f, den = 0.0f;
  for (int c = 0; c < nv; c++) {
    float mc = p[c * PSTRIDE + 64];
    float wgt = expf(mc - m);
    num += wgt * p[c * PSTRIDE + d];
    den += wgt * p[c * PSTRIDE + 65];
  }
  out[((size_t)bh * D_ + d) * L_ + sel] = num / den;
}

extern "C" void kernel_launch(void* const* d_in, const int* in_sizes, int n_in,
                              void* d_out, int out_size, void* d_ws, size_t ws_size,
                              hipStream_t stream) {
  const float* q = (const float*)d_in[0];
  const float* k = (const float*)d_in[1];
  const float* v = (const float*)d_in[2];
  float* out = (float*)d_out;

  const size_t NT = (size_t)BH * L_ * D_;     // 8388608 floats per tensor
  float* qt = (float*)d_ws;
  float* kt = qt + NT;
  float* M  = kt + NT;                         // BH*L floats
  int* idx  = (int*)(M + (size_t)BH * L_);     // 4096*25 ints
  int* ssel = idx + L_ * U_PART;               // BH*45 ints (sorted desc per bh)
  float* part = (float*)(ssel + BH * TOPU);    // 1440*32*68 floats (~12.5 MB)

  uint32_t k2a, k2b;
#if JAX_THREEFRY_PARTITIONABLE
  tf2x32(0u, 42u, 0u, 1u, k2a, k2b);
#else
  uint32_t a0, a1, b0, b1;
  tf2x32(0u, 42u, 0u, 2u, a0, a1);
  tf2x32(0u, 42u, 1u, 3u, b0, b1);
  k2a = a1; k2b = b1;
#endif

#if JAX_THREEFRY_PARTITIONABLE
  sample_idx_kernel<<<(L_ * U_PART + 255) / 256, 256, 0, stream>>>(idx, k2a, k2b);
#else
  sample_idx_kernel<<<(L_ * U_PART / 2 + 255) / 256, 256, 0, stream>>>(idx, k2a, k2b);
#endif
  transpose_cumsum<<<dim3(L_ / 64, BH, 3), 256, 0, stream>>>(q, k, v, qt, kt, out);
  m_kernel<<<BH * L_ / 16, 256, 0, stream>>>(qt, kt, idx, M);
  topk_kernel<<<BH, 256, 0, stream>>>(M, ssel);
  update_partial<<<BH * 16, 256, 0, stream>>>(qt, k, v, ssel, part);
  update_combine<<<(BH * TOPU + 3) / 4, 256, 0, stream>>>(part, ssel, out);
}